// Round 3
// baseline (1403.257 us; speedup 1.0000x reference)
//
#include <hip/hip_runtime.h>

#define HH 32
#define LOG2E 1.44269504088896340736f

typedef float v2f __attribute__((ext_vector_type(2)));

// DPP: quad_perm broadcasts (gate q = lane&3) and row rotates (16-lane rows)
#define DPPF(v, ctrl) \
    __int_as_float(__builtin_amdgcn_update_dpp(0, __float_as_int(v), (ctrl), 0xF, 0xF, true))
#define QP_B0 0x00
#define QP_B1 0x55
#define QP_B2 0xAA
#define QP_B3 0xFF
#define DPP_ROR4  0x124
#define DPP_ROR8  0x128
#define SWZ(v, pat) __int_as_float(__builtin_amdgcn_ds_swizzle(__float_as_int(v), (pat)))

__device__ __forceinline__ float hw_exp2(float x) {
    float r; asm("v_exp_f32 %0, %1" : "=v"(r) : "v"(x)); return r;
}
__device__ __forceinline__ float sigm_e(float z, float e) {
    return __builtin_amdgcn_rcpf(1.0f + hw_exp2(z * e));
}
__device__ __forceinline__ v2f pk_fma(v2f a, v2f b, v2f c) {
    return __builtin_elementwise_fma(a, b, c);   // v_pk_fma_f32
}

// sum of per-lane pr over the wave's 16 chL groups (pr redundant across q)
__device__ __forceinline__ float out_reduce(float p) {
    p += DPPF(p, DPP_ROR4);
    p += DPPF(p, DPP_ROR8);
    p += SWZ(p, 0x401F);             // xor16
    p += __shfl_xor(p, 32, 64);
    return p;
}

// dot of one 32-vector (LDS, broadcast) with 16 v2f weight regs
__device__ __forceinline__ float dotv(const float* va, const v2f* m) {
    const float4* pa = (const float4*)va;
    float4 a = pa[0], b = pa[1];
    v2f s0 = (v2f){a.x,a.y} * m[0], s1 = (v2f){a.z,a.w} * m[1];
    v2f s2 = (v2f){b.x,b.y} * m[2], s3 = (v2f){b.z,b.w} * m[3];
#pragma unroll
    for (int rr = 2; rr < 8; rr += 2) {
        float4 c = pa[rr], d = pa[rr+1];
        s0 = pk_fma((v2f){c.x,c.y}, m[2*rr],   s0);
        s1 = pk_fma((v2f){c.z,c.w}, m[2*rr+1], s1);
        s2 = pk_fma((v2f){d.x,d.y}, m[2*rr+2], s2);
        s3 = pk_fma((v2f){d.z,d.w}, m[2*rr+3], s3);
    }
    v2f t = (s0 + s1) + (s2 + s3);
    return t.x + t.y;
}

// fused: dot(va,ma) + dot(vb,mb), interleaved loads to bound live registers
__device__ __forceinline__ float dotv2f(const float* va, const v2f* ma,
                                        const float* vb, const v2f* mb) {
    const float4* pa = (const float4*)va;
    const float4* pb = (const float4*)vb;
    float4 a = pa[0], b = pb[0];
    v2f s0 = (v2f){a.x,a.y} * ma[0], s1 = (v2f){a.z,a.w} * ma[1];
    v2f s2 = (v2f){b.x,b.y} * mb[0], s3 = (v2f){b.z,b.w} * mb[1];
#pragma unroll
    for (int rr = 1; rr < 8; ++rr) {
        float4 c = pa[rr], d = pb[rr];
        s0 = pk_fma((v2f){c.x,c.y}, ma[2*rr],   s0);
        s1 = pk_fma((v2f){c.z,c.w}, ma[2*rr+1], s1);
        s2 = pk_fma((v2f){d.x,d.y}, mb[2*rr],   s2);
        s3 = pk_fma((v2f){d.z,d.w}, mb[2*rr+1], s3);
    }
    v2f t = (s0 + s1) + (s2 + s3);
    return t.x + t.y;
}

// one-row gate: lane holds z for its (gate q, channel ch) row; quad broadcast
__device__ __forceinline__ float gate1(float z, float es, float mm, float cc, float& c) {
    float ac = fmaf(mm, sigm_e(z, es), cc);
    float gi = DPPF(ac, QP_B0), gf = DPPF(ac, QP_B1);
    float gg = DPPF(ac, QP_B2), go = DPPF(ac, QP_B3);
    c = fmaf(gf, c, gi * gg);
    return go * fmaf(2.0f, sigm_e(c, -2.0f * LOG2E), -1.0f);
}

// 4 waves/block, 1 batch elem/block. Waves 0,1 = cell1 (half 0,1); 2,3 = cell2.
// Lane owns ONE row: q=lane&3 (gate), ch=(lane>>2)+16*half, row=(q<<5)|ch.
// Weights: 16 v2f per matrix per lane -> fully register-resident under 128 VGPR.
// TF: lockstep 1-barrier/step, cell2 lags 1 step (double-buffered h1/h2).
// AR: 2 barriers/step (serial h2->x->cell1->h1->cell2 chain), halved per-wave work.
__global__ __launch_bounds__(256, 4)
void lstm_seq_kernel(const float* __restrict__ input,
                     const float* __restrict__ W_ih1, const float* __restrict__ W_hh1,
                     const float* __restrict__ b_ih1, const float* __restrict__ b_hh1,
                     const float* __restrict__ W_ih2, const float* __restrict__ W_hh2,
                     const float* __restrict__ b_ih2, const float* __restrict__ b_hh2,
                     const float* __restrict__ W_lin, const float* __restrict__ b_lin,
                     float* __restrict__ out, int T, int total)
{
    const int b    = blockIdx.x;
    const int tid  = threadIdx.x;
    const int wv   = tid >> 6;         // 0..3
    const int lane = tid & 63;
    const int cell = wv >> 1;          // 0 = cell1, 1 = cell2
    const int half = wv & 1;
    const int q    = lane & 3;
    const int ch   = (lane >> 2) + (half << 4);   // 0..31
    const int row  = (q << 5) | ch;

    __shared__ __align__(16) float h1buf[2][HH];
    __shared__ __align__(16) float h2buf[2][HH];
    __shared__ float outP[2][2];

    if (tid < HH) {
        h1buf[0][tid] = 0.f; h1buf[1][tid] = 0.f;
        h2buf[0][tid] = 0.f; h2buf[1][tid] = 0.f;
    }
    if (tid < 4) outP[tid >> 1][tid & 1] = 0.f;

    const bool  isg = (q == 2);
    const float es  = isg ? (-2.0f * LOG2E) : (-LOG2E);
    const float mm  = isg ? 2.0f : 1.0f;
    const float cc  = isg ? -1.0f : 0.0f;

    // weight loads via uniform pointer select (non-divergent code)
    // cell1: m1 = Whh1 row, m2 = W_lin broadcast (AR feedback dot)
    // cell2: m1 = Wih2 row, m2 = Whh2 row
    const v2f* m1p = (const v2f*)((cell == 0 ? W_hh1 : W_ih2) + row * HH);
    const v2f* m2p = (cell == 0) ? (const v2f*)W_lin
                                 : (const v2f*)(W_hh2 + row * HH);
    v2f m1[16], m2[16];
#pragma unroll
    for (int r = 0; r < 16; ++r) { m1[r] = m1p[r]; m2[r] = m2p[r]; }

    const float wx  = W_ih1[row];                 // used by cell1 only
    const float bb  = (cell == 0) ? (b_ih1[row] + b_hh1[row])
                                  : (b_ih2[row] + b_hh2[row]);
    const float wlc = W_lin[ch];                  // used by cell2 TF out partial
    const float blin = b_lin[0];

    float cst = 0.f;                // c1 (cell1 waves) / c2 (cell2 waves)
    float pAR = 0.f;                // cell1: carried Whh1·h1 dot for AR entry

    const float* __restrict__ inp  = input + (size_t)b * T;
    float* __restrict__       outp = out   + (size_t)b * total;

    // ================= Teacher-forced: lockstep, 1 barrier/step =================
    float xcur = inp[0];
    for (int t = 0; t <= T; ++t) {
        __syncthreads();
        if (cell == 0) {
            if (t < T) {
                float pd = dotv(h1buf[(t + 1) & 1], m1);     // Whh1·h1(t-1)
                float x = xcur;
                int tn = t + 1;
                xcur = inp[tn < T ? tn : 0];                 // prefetch, off-path
                float z1 = fmaf(x, wx, bb + pd);
                float h = gate1(z1, es, mm, cc, cst);
                if (q == 0) h1buf[t & 1][ch] = h;
            } else {
                pAR = dotv(h1buf[(T - 1) & 1], m1);          // carry into AR
            }
        } else {
            if (t >= 1) {
                // h2(t-1) = cell2(h1(t-1), h2(t-2))
                float zd = dotv2f(h1buf[(t - 1) & 1], m1, h2buf[t & 1], m2);
                float z2 = bb + zd;
                float h = gate1(z2, es, mm, cc, cst);
                if (q == 0) h2buf[(t - 1) & 1][ch] = h;
                float po = out_reduce(h * wlc);
                if (lane == 0) outP[(t - 1) & 1][half] = po;
            }
            if (t >= 2 && wv == 2 && lane == 0)
                outp[t - 2] = outP[t & 1][0] + outP[t & 1][1] + blin;
        }
    }

    // ================= Autoregressive: 2 barriers/step =================
    float* h2x = h2buf[(T - 1) & 1];   // persistent h2 exchange
    float* h1x = h1buf[0];             // reuse as h1 exchange
    float sAR = 0.f;                   // cell2: Whh2·h2(t-1), refreshed each B1-half

    for (int t = T; t < total; ++t) {
        __syncthreads();                           // B1: h2x = h2(t-1) visible
        if (cell == 0) {
            float xo = dotv(h2x, m2) + blin;       // out(t-1), per-lane redundant
            if (wv == 0 && lane == 0) outp[t - 1] = xo;
            float z1 = fmaf(xo, wx, bb + pAR);
            float h = gate1(z1, es, mm, cc, cst);
            if (q == 0) h1x[ch] = h;
        } else {
            sAR = dotv(h2x, m2);                   // Whh2·h2(t-1), overlapped
        }
        __syncthreads();                           // B2: h1x = h1(t) visible
        if (cell == 0) {
            pAR = dotv(h1x, m1);                   // Whh1·h1(t) for next step
        } else {
            float z2 = bb + sAR + dotv(h1x, m1);
            float h = gate1(z2, es, mm, cc, cst);
            if (q == 0) h2x[ch] = h;
        }
    }
    // tail: out(total-1) = Wlin·h2(total-1) + blin
    __syncthreads();
    if (wv == 0) {
        float xo = dotv(h2x, m2) + blin;
        if (lane == 0) outp[total - 1] = xo;
    }
}

extern "C" void kernel_launch(void* const* d_in, const int* in_sizes, int n_in,
                              void* d_out, int out_size, void* d_ws, size_t ws_size,
                              hipStream_t stream) {
    const int B = 1024;                 // fixed by the source module
    const int T = in_sizes[0] / B;      // 999
    const int total = out_size / B;     // T + future = 1999

    lstm_seq_kernel<<<dim3(B), dim3(256), 0, stream>>>(
        (const float*)d_in[0],
        (const float*)d_in[1], (const float*)d_in[2],
        (const float*)d_in[3], (const float*)d_in[4],
        (const float*)d_in[5], (const float*)d_in[6],
        (const float*)d_in[7], (const float*)d_in[8],
        (const float*)d_in[9], (const float*)d_in[10],
        (float*)d_out, T, total);
}